// Round 4
// baseline (128.443 us; speedup 1.0000x reference)
//
#include <hip/hip_runtime.h>
#include <stdint.h>

// ---------------------------------------------------------------------------
// AudioVisualModel fused loss on MI355X — R4: 32x32x16 MFMA, n_aw=2 LDS sharing.
// B=16, Na=128, T=10, Nv=196, D=256.
// prep:  normalize -> bf16. 4 rows/wave, 16 lanes/row. Visual t-padded to 256
//        rows (2560/panel), rows pre-swizzled (16B-unit ^ row&7).
// main:  512 blocks = (x, y, t-half). 4 waves = 2 audio-halves x 2 visual
//        slots. af[2][16] in regs (128 VGPR), 64 audio rows/wave.
//        Chunks = 64 visual rows (32KB), double-buffered global_load_lds,
//        raw s_barrier + counted s_waitcnt vmcnt(8). ft==7 frags (all pad)
//        skipped. Per-(col,t) max via LDS atomicMax.
// final: 16x16 InfoNCE + reg terms.
// ---------------------------------------------------------------------------

typedef __bf16 bf16x8 __attribute__((ext_vector_type(8)));
typedef float  f32x16 __attribute__((ext_vector_type(16)));

#define WS_A_OFF  ((size_t)0)                          // 2048 x 512B = 1 MB
#define WS_V_OFF  ((size_t)(1u<<20))                   // 16 x 2560 x 512B = 21 MB
#define WS_CP_OFF (WS_V_OFF + (size_t)16*2560*512)     // clip parts [1024] + nn [1024]

#define NINF (-3.4e38f)

// order-preserving float<->int encoding for integer atomicMax
__device__ __forceinline__ int fenc(float f) {
    int i = __float_as_int(f);
    return i >= 0 ? i : (i ^ 0x7fffffff);
}
__device__ __forceinline__ float fdec(int i) {
    return __int_as_float(i >= 0 ? i : (i ^ 0x7fffffff));
}
__device__ __forceinline__ void gld_lds16(const char* g, char* l) {
    __builtin_amdgcn_global_load_lds(
        (const __attribute__((address_space(1))) void*)g,
        (__attribute__((address_space(3))) void*)l, 16, 0, 0);
}

// ---------------------------------------------------------------------------
// prep: 4 rows per wave, 16 lanes per row (lane sub = position, g = row-in-wave).
// rows [0,2048): audio (linear). rows [2048, 2048+40960): visual (padded+swizzled).
__global__ __launch_bounds__(256) void prep_kernel(const float* __restrict__ audio,
                                                   const float* __restrict__ visual,
                                                   char* __restrict__ ws)
{
    const int wave = blockIdx.x * 4 + (threadIdx.x >> 6);
    const int lane = threadIdx.x & 63;
    const int g    = lane >> 4;
    const int sub  = lane & 15;
    const int row  = wave * 4 + g;          // [0, 43008)

    float4 v0 = {0,0,0,0}, v1 = {0,0,0,0}, v2 = {0,0,0,0}, v3 = {0,0,0,0};
    size_t dst0, dst1;
    if (row < 2048) {
        const float* s = audio + (size_t)row * 256 + sub * 16;
        v0 = *(const float4*)(s);  v1 = *(const float4*)(s + 4);
        v2 = *(const float4*)(s + 8); v3 = *(const float4*)(s + 12);
        dst0 = WS_A_OFF + (size_t)row * 512 + sub * 32;
        dst1 = dst0 + 16;
    } else {
        const int vr  = row - 2048;          // [0, 40960)
        const int y   = vr / 2560;
        const int rem = vr - y * 2560;
        const int t   = rem >> 8;
        const int vv  = rem & 255;
        if (vv < 196) {
            const float* s = visual + (size_t)((y*10 + t)*196 + vv) * 256 + sub * 16;
            v0 = *(const float4*)(s);  v1 = *(const float4*)(s + 4);
            v2 = *(const float4*)(s + 8); v3 = *(const float4*)(s + 12);
        }
        const size_t base = WS_V_OFF + (size_t)vr * 512;
        const int u0 = (2*sub)     ^ (vr & 7);
        const int u1 = (2*sub + 1) ^ (vr & 7);
        dst0 = base + ((size_t)u0 << 4);
        dst1 = base + ((size_t)u1 << 4);
    }

    float ss = v0.x*v0.x + v0.y*v0.y + v0.z*v0.z + v0.w*v0.w
             + v1.x*v1.x + v1.y*v1.y + v1.z*v1.z + v1.w*v1.w
             + v2.x*v2.x + v2.y*v2.y + v2.z*v2.z + v2.w*v2.w
             + v3.x*v3.x + v3.y*v3.y + v3.z*v3.z + v3.w*v3.w;
    #pragma unroll
    for (int m = 1; m < 16; m <<= 1) ss += __shfl_xor(ss, m);
    const float sc = 1.0f / fmaxf(sqrtf(ss), 1e-12f);   // zero row -> 0*huge = 0

    bf16x8 oa, ob;
    oa[0]=(__bf16)(v0.x*sc); oa[1]=(__bf16)(v0.y*sc); oa[2]=(__bf16)(v0.z*sc); oa[3]=(__bf16)(v0.w*sc);
    oa[4]=(__bf16)(v1.x*sc); oa[5]=(__bf16)(v1.y*sc); oa[6]=(__bf16)(v1.z*sc); oa[7]=(__bf16)(v1.w*sc);
    ob[0]=(__bf16)(v2.x*sc); ob[1]=(__bf16)(v2.y*sc); ob[2]=(__bf16)(v2.z*sc); ob[3]=(__bf16)(v2.w*sc);
    ob[4]=(__bf16)(v3.x*sc); ob[5]=(__bf16)(v3.y*sc); ob[6]=(__bf16)(v3.z*sc); ob[7]=(__bf16)(v3.w*sc);
    *(uint4*)(ws + dst0) = __builtin_bit_cast(uint4, oa);
    *(uint4*)(ws + dst1) = __builtin_bit_cast(uint4, ob);
}

// ---------------------------------------------------------------------------
#define STAGE(c_, buf_) do {                                          \
    const char* s_ = vbase + (size_t)(c_) * 32768 + tid * 16;         \
    char* d_ = smem + ((buf_) << 15) + tid * 16;                      \
    gld_lds16(s_,         d_);         gld_lds16(s_ +  4096, d_ +  4096); \
    gld_lds16(s_ +  8192, d_ +  8192); gld_lds16(s_ + 12288, d_ + 12288); \
    gld_lds16(s_ + 16384, d_ + 16384); gld_lds16(s_ + 20480, d_ + 20480); \
    gld_lds16(s_ + 24576, d_ + 24576); gld_lds16(s_ + 28672, d_ + 28672); \
} while (0)

__global__ __launch_bounds__(256, 2) void main_kernel(char* __restrict__ ws)
{
    extern __shared__ __align__(16) char smem[];     // 2 x 32768
    __shared__ int part_lds[640];                    // [128 audio cols][5 t]
    __shared__ float red[8];

    const int tid  = threadIdx.x;
    const int lane = tid & 63;
    const int wid  = tid >> 6;
    const int aw   = wid & 1;            // audio half (64 rows)
    const int vw   = wid >> 1;           // visual slot in chunk (32 rows)
    const int l31  = lane & 31;
    const int hi   = lane >> 5;

    const int b = blockIdx.x;
    const int xcd = b & 7, slot = b >> 3;        // slot in [0,64)
    const int y = xcd * 2 + (slot >> 5);         // each XCD: 2 y-panels (L2)
    const int x = (slot >> 1) & 15;
    const int h = slot & 1;                      // t-half: t in [5h, 5h+5)

    for (int i = tid; i < 640; i += 256) part_lds[i] = (int)0x80000000;

    // audio fragments: 64 rows x 256 k -> af[2 strips][16 ksteps], 128 VGPR
    bf16x8 af0[16], af1[16];
    {
        const char* ab = ws + WS_A_OFF + (size_t)(x*128 + aw*64) * 512;
        #pragma unroll
        for (int k = 0; k < 16; ++k) {
            af0[k] = __builtin_bit_cast(bf16x8,
                *(const uint4*)(ab + l31*512 + k*32 + hi*16));
            af1[k] = __builtin_bit_cast(bf16x8,
                *(const uint4*)(ab + (32 + l31)*512 + k*32 + hi*16));
        }
    }
    asm volatile("s_waitcnt vmcnt(0)" ::: "memory");

    const char* vbase = ws + WS_V_OFF + ((size_t)y * 2560 + (size_t)h * 1280) * 512;

    float nn = 0.f, rmax0 = NINF, rmax1 = NINF;

    STAGE(0, 0);

    for (int c = 0; c < 20; ++c) {
        if (c < 19) {
            STAGE(c + 1, (c + 1) & 1);
            asm volatile("s_waitcnt vmcnt(8)" ::: "memory");   // stage(c) done
        } else {
            asm volatile("s_waitcnt vmcnt(0)" ::: "memory");
        }
        __builtin_amdgcn_s_barrier();

        const int f  = 2*c + vw;                 // frag in [0,40)
        const int ft = f & 7;
        if (ft != 7) {                           // ft==7: all-pad frag, skip
            const char* bb = smem + ((c & 1) << 15) + ((vw*32 + l31) * 512);
            const int sx = (l31 & 7) << 4;       // read-side XOR

            f32x16 acc0 = {}, acc1 = {};
            #pragma unroll
            for (int hf = 0; hf < 2; ++hf) {
                bf16x8 vf[8];
                #pragma unroll
                for (int k8 = 0; k8 < 8; ++k8) {
                    const int u = (((hf*8 + k8)*2 + hi) << 4) ^ sx;
                    vf[k8] = __builtin_bit_cast(bf16x8, *(const uint4*)(bb + u));
                }
                #pragma unroll
                for (int k8 = 0; k8 < 8; ++k8) {
                    acc0 = __builtin_amdgcn_mfma_f32_32x32x16_bf16(vf[k8], af0[hf*8 + k8], acc0, 0,0,0);
                    acc1 = __builtin_amdgcn_mfma_f32_32x32x16_bf16(vf[k8], af1[hf*8 + k8], acc1, 0,0,0);
                }
            }

            // nonneg: pad rows are exact zeros -> contribute 0
            #pragma unroll
            for (int i = 0; i < 16; ++i) {
                const float g0 = fminf(acc0[i], 0.f);
                const float g1 = fminf(acc1[i], 0.f);
                nn = fmaf(g0, g0, nn);
                nn = fmaf(g1, g1, nn);
            }
            // max over visual rows in this frag (mask pads in ft==6)
            float m0, m1;
            if (ft == 6) {   // valid rows 0-3 -> regs 0-3, hi==0 only
                m0 = fmaxf(fmaxf(acc0[0], acc0[1]), fmaxf(acc0[2], acc0[3]));
                m1 = fmaxf(fmaxf(acc1[0], acc1[1]), fmaxf(acc1[2], acc1[3]));
                if (hi) { m0 = NINF; m1 = NINF; }
            } else {
                float a0 = fmaxf(fmaxf(acc0[0], acc0[1]), fmaxf(acc0[2], acc0[3]));
                float a1 = fmaxf(fmaxf(acc0[4], acc0[5]), fmaxf(acc0[6], acc0[7]));
                float a2 = fmaxf(fmaxf(acc0[8], acc0[9]), fmaxf(acc0[10], acc0[11]));
                float a3 = fmaxf(fmaxf(acc0[12], acc0[13]), fmaxf(acc0[14], acc0[15]));
                m0 = fmaxf(fmaxf(a0, a1), fmaxf(a2, a3));
                float b0 = fmaxf(fmaxf(acc1[0], acc1[1]), fmaxf(acc1[2], acc1[3]));
                float b1 = fmaxf(fmaxf(acc1[4], acc1[5]), fmaxf(acc1[6], acc1[7]));
                float b2 = fmaxf(fmaxf(acc1[8], acc1[9]), fmaxf(acc1[10], acc1[11]));
                float b3 = fmaxf(fmaxf(acc1[12], acc1[13]), fmaxf(acc1[14], acc1[15]));
                m1 = fmaxf(fmaxf(b0, b1), fmaxf(b2, b3));
            }
            rmax0 = fmaxf(rmax0, m0);
            rmax1 = fmaxf(rmax1, m1);
        }

        if ((c & 3) == 3) {              // end of t (8 frags) for all waves
            const int tl = c >> 2;       // local t in [0,5)
            float vv0 = fmaxf(rmax0, __shfl_xor(rmax0, 32));
            float vv1 = fmaxf(rmax1, __shfl_xor(rmax1, 32));
            if (hi == 0) {
                atomicMax(&part_lds[(aw*64 + l31) * 5 + tl],      fenc(vv0));
                atomicMax(&part_lds[(aw*64 + 32 + l31) * 5 + tl], fenc(vv1));
            }
            rmax0 = NINF; rmax1 = NINF;
        }
        asm volatile("" ::: "memory");
        __builtin_amdgcn_s_barrier();    // buf[cur] reads done before restage
    }

    __syncthreads();

    float sum = 0.f;
    for (int i = tid; i < 640; i += 256) sum += fdec(part_lds[i]);
    #pragma unroll
    for (int m = 1; m < 64; m <<= 1) {
        sum += __shfl_xor(sum, m);
        nn  += __shfl_xor(nn, m);
    }
    if (lane == 0) { red[wid] = sum; red[4 + wid] = nn; }
    __syncthreads();
    if (tid == 0) {
        float S = 0.f, N = 0.f;
        #pragma unroll
        for (int w = 0; w < 4; ++w) { S += red[w]; N += red[4 + w]; }
        float* cp = (float*)(ws + WS_CP_OFF);
        cp[(x*16 + y)*2 + h]       = S;
        cp[512 + (x*16 + y)*2 + h] = N;
    }
}

// ---------------------------------------------------------------------------
// final: 16x16 InfoNCE + regularizers -> 3 scalars
__global__ void final_kernel(const char* __restrict__ ws,
                             const float* __restrict__ temp,
                             float* __restrict__ out)
{
    __shared__ float cs[16][17];
    __shared__ float nnred[256];
    __shared__ float lse_r[16], lse_c[16];
    const int tid = threadIdx.x;
    const float T = temp[0];
    const float* cp = (const float*)(ws + WS_CP_OFF);
    cs[tid >> 4][tid & 15] = (cp[tid*2] + cp[tid*2 + 1]) / (1280.0f * T);
    nnred[tid] = cp[512 + tid*2] + cp[512 + tid*2 + 1];
    __syncthreads();
    for (int s = 128; s > 0; s >>= 1) {
        if (tid < s) nnred[tid] += nnred[tid + s];
        __syncthreads();
    }
    if (tid < 16) {
        float m = NINF;
        for (int j = 0; j < 16; ++j) m = fmaxf(m, cs[tid][j]);
        float s = 0.f;
        for (int j = 0; j < 16; ++j) s += expf(cs[tid][j] - m);
        lse_r[tid] = m + logf(s);
    } else if (tid < 32) {
        const int c = tid - 16;
        float m = NINF;
        for (int j = 0; j < 16; ++j) m = fmaxf(m, cs[j][c]);
        float s = 0.f;
        for (int j = 0; j < 16; ++j) s += expf(cs[j][c] - m);
        lse_c[c] = m + logf(s);
    }
    __syncthreads();
    if (tid == 0) {
        float acc = 0.f;
        for (int i = 0; i < 16; ++i)
            acc += (lse_r[i] - cs[i][i]) + (lse_c[i] - cs[i][i]);
        const float contrastive = 0.5f * acc * (1.0f / 16.0f);
        const float l_nonneg = nnred[0] / (64225280.0f * T * T);
        const float lt = logf(T);
        float tl = fmaxf(-lt, 0.f); tl = tl * tl; tl = tl * tl;
        float th = fmaxf(lt - 1.0986122886681098f, 0.f); th = th * th; th = th * th;
        const float reg = l_nonneg + tl + th;
        out[0] = contrastive + 0.3f * reg;
        out[1] = contrastive;
        out[2] = reg;
    }
}

// ---------------------------------------------------------------------------
extern "C" void kernel_launch(void* const* d_in, const int* in_sizes, int n_in,
                              void* d_out, int out_size, void* d_ws, size_t ws_size,
                              hipStream_t stream)
{
    const float* audio  = (const float*)d_in[0];
    const float* visual = (const float*)d_in[1];
    const float* temp   = (const float*)d_in[2];
    char* ws = (char*)d_ws;

    prep_kernel<<<2688, 256, 0, stream>>>(audio, visual, ws);   // 43008 rows
    main_kernel<<<512, 256, 65536, stream>>>(ws);               // (x, y, t-half)
    final_kernel<<<1, 256, 0, stream>>>(ws, temp, (float*)d_out);
}

// Round 5
// 121.516 us; speedup vs baseline: 1.0570x; 1.0570x over previous
//
#include <hip/hip_runtime.h>
#include <stdint.h>

// ---------------------------------------------------------------------------
// AudioVisualModel fused loss on MI355X — R5: fp8 e4m3 MFMA, 4 waves/SIMD.
// B=16, Na=128, T=10, Nv=196, D=256.
// prep:  normalize (f32) -> fp8 e4m3. Audio linear [2048][256B]. Visual padded
//        per-t to 256 rows (2560/panel), 8B-unit swizzle u^(row&31).
// main:  1024 blocks = (x2: 64 audio rows, y, t-half). 4 waves = 2 aw x 2 vw.
//        af[16] in regs (32 VGPR). Visual chunks 64 rows (16KB) double-buffered
//        via global_load_lds, raw s_barrier + counted s_waitcnt vmcnt(4).
//        4 blocks/CU (133KB LDS) -> 16 waves/CU -> MFMA/VALU overlap across
//        independent blocks. Per-(col,t) max via LDS atomicMax.
// final: 16x16 InfoNCE + reg terms.
// ---------------------------------------------------------------------------

typedef float f32x16 __attribute__((ext_vector_type(16)));

#define WS_A_OFF  ((size_t)0)                          // 2048 x 256B = 512KB
#define WS_V_OFF  ((size_t)(1u<<20))                   // 16 x 2560 x 256B = 10.5MB
#define WS_CP_OFF (WS_V_OFF + (size_t)16*2560*256)     // clip [1024] + nn [1024]

#define NINF (-3.4e38f)

__device__ __forceinline__ int fenc(float f) {
    int i = __float_as_int(f);
    return i >= 0 ? i : (i ^ 0x7fffffff);
}
__device__ __forceinline__ float fdec(int i) {
    return __int_as_float(i >= 0 ? i : (i ^ 0x7fffffff));
}
__device__ __forceinline__ void gld_lds16(const char* g, char* l) {
    __builtin_amdgcn_global_load_lds(
        (const __attribute__((address_space(1))) void*)g,
        (__attribute__((address_space(3))) void*)l, 16, 0, 0);
}

// ---------------------------------------------------------------------------
// prep: one wave = 2 rows, 32 lanes/row, 8 f32 -> 8 fp8 per lane.
// rows [0,2048): audio (linear). [2048, 2048+40960): visual (padded+swizzled).
__global__ __launch_bounds__(256) void prep_kernel(const float* __restrict__ audio,
                                                   const float* __restrict__ visual,
                                                   char* __restrict__ ws)
{
    const int wave = blockIdx.x * 4 + (threadIdx.x >> 6);
    const int lane = threadIdx.x & 63;
    const int half = lane >> 5;
    const int sub  = lane & 31;
    const int row  = wave * 2 + half;          // [0, 43008)

    float f[8];
    #pragma unroll
    for (int i = 0; i < 8; ++i) f[i] = 0.f;
    size_t dst;
    if (row < 2048) {
        const float* s = audio + (size_t)row * 256 + sub * 8;
        *(float4*)(f)     = *(const float4*)(s);
        *(float4*)(f + 4) = *(const float4*)(s + 4);
        dst = WS_A_OFF + (size_t)row * 256 + sub * 8;
    } else {
        const int vr  = row - 2048;            // [0, 40960)
        const int y   = vr / 2560;
        const int rem = vr - y * 2560;
        const int t   = rem >> 8;
        const int vv  = rem & 255;
        if (vv < 196) {
            const float* s = visual + (size_t)((y*10 + t)*196 + vv) * 256 + sub * 8;
            *(float4*)(f)     = *(const float4*)(s);
            *(float4*)(f + 4) = *(const float4*)(s + 4);
        }
        dst = WS_V_OFF + (size_t)vr * 256 + (size_t)((sub ^ (vr & 31)) << 3);
    }

    float ss = 0.f;
    #pragma unroll
    for (int i = 0; i < 8; ++i) ss += f[i] * f[i];
    #pragma unroll
    for (int m = 1; m < 32; m <<= 1) ss += __shfl_xor(ss, m);   // within 32-lane half
    const float sc = 1.0f / fmaxf(sqrtf(ss), 1e-12f);           // zero row -> 0

    int w0 = __builtin_amdgcn_cvt_pk_fp8_f32(f[0]*sc, f[1]*sc, 0, false);
    w0     = __builtin_amdgcn_cvt_pk_fp8_f32(f[2]*sc, f[3]*sc, w0, true);
    int w1 = __builtin_amdgcn_cvt_pk_fp8_f32(f[4]*sc, f[5]*sc, 0, false);
    w1     = __builtin_amdgcn_cvt_pk_fp8_f32(f[6]*sc, f[7]*sc, w1, true);
    *(uint2*)(ws + dst) = make_uint2((unsigned)w0, (unsigned)w1);
}

// ---------------------------------------------------------------------------
#define STAGE(c_, buf_) do {                                          \
    const char* s_ = vbase + (size_t)(c_) * 16384 + tid * 16;         \
    char* d_ = &smem[buf_][0] + tid * 16;                             \
    gld_lds16(s_,         d_);         gld_lds16(s_ +  4096, d_ +  4096); \
    gld_lds16(s_ +  8192, d_ +  8192); gld_lds16(s_ + 12288, d_ + 12288); \
} while (0)

__global__ __launch_bounds__(256, 4) void main_kernel(char* __restrict__ ws)
{
    __shared__ __align__(16) char smem[2][16384];
    __shared__ int part[320];                    // [64 audio cols][5 t]
    __shared__ float red[8];

    const int tid  = threadIdx.x;
    const int lane = tid & 63;
    const int wid  = tid >> 6;
    const int aw   = wid & 1;            // audio strip (32 rows)
    const int vw   = wid >> 1;           // visual frag slot in chunk (32 rows)
    const int l31  = lane & 31;
    const int hi   = lane >> 5;

    const int b = blockIdx.x;
    const int xcd = b & 7, s = b >> 3;           // s in [0,128)
    const int y  = xcd * 2 + (s >> 6);           // each XCD: 2 y-panels (L2)
    const int x2 = (s & 63) >> 1;                // 64-row audio group [0,32)
    const int h  = s & 1;                        // t-half

    for (int i = tid; i < 320; i += 256) part[i] = (int)0x80000000;

    // audio fragments: 32 rows x K=256 -> af[16], 32 VGPR
    uint64_t af[16];
    {
        const char* ab = ws + WS_A_OFF + (size_t)(x2*64 + aw*32 + l31) * 256 + hi*8;
        #pragma unroll
        for (int k = 0; k < 16; ++k)
            af[k] = *(const uint64_t*)(ab + k*16);
    }
    asm volatile("s_waitcnt vmcnt(0)" ::: "memory");
    __syncthreads();                             // af done + part init visible

    const char* vbase = ws + WS_V_OFF + ((size_t)y * 2560 + (size_t)h * 1280) * 256;

    float nn = 0.f, rmax = NINF;

    STAGE(0, 0);

    for (int c = 0; c < 20; ++c) {
        if (c < 19) {
            STAGE(c + 1, (c + 1) & 1);
            asm volatile("s_waitcnt vmcnt(4)" ::: "memory");   // stage(c) landed
        } else {
            asm volatile("s_waitcnt vmcnt(0)" ::: "memory");
        }
        __builtin_amdgcn_s_barrier();

        const int f  = 2*c + vw;                 // frag in [0,40)
        const int ft = f & 7;
        if (ft != 7) {                           // ft==7: all-pad frag, skip
            const char* bb = &smem[c & 1][0] + (vw*32 + l31) * 256;
            uint64_t vf[16];
            #pragma unroll
            for (int k = 0; k < 16; ++k)
                vf[k] = *(const uint64_t*)(bb + (((k*2 + hi) ^ l31) << 3));

            f32x16 acc = {};
            #pragma unroll
            for (int k = 0; k < 16; ++k)
                acc = __builtin_amdgcn_mfma_f32_32x32x16_fp8_fp8(
                    (long)vf[k], (long)af[k], acc, 0, 0, 0);

            // nonneg: pad rows are exact zeros -> contribute 0
            #pragma unroll
            for (int i = 0; i < 16; ++i) {
                const float g = fminf(acc[i], 0.f);
                nn = fmaf(g, g, nn);
            }
            float m;
            if (ft == 6) {   // valid visual rows 0-3 -> regs 0-3 at hi==0
                m = fmaxf(fmaxf(acc[0], acc[1]), fmaxf(acc[2], acc[3]));
                if (hi) m = NINF;
            } else {
                float a0 = fmaxf(fmaxf(acc[0], acc[1]),   fmaxf(acc[2], acc[3]));
                float a1 = fmaxf(fmaxf(acc[4], acc[5]),   fmaxf(acc[6], acc[7]));
                float a2 = fmaxf(fmaxf(acc[8], acc[9]),   fmaxf(acc[10], acc[11]));
                float a3 = fmaxf(fmaxf(acc[12], acc[13]), fmaxf(acc[14], acc[15]));
                m = fmaxf(fmaxf(a0, a1), fmaxf(a2, a3));
            }
            rmax = fmaxf(rmax, m);
        }

        if ((c & 3) == 3) {              // end of t (4 chunks = 8 frags)
            const int tl = c >> 2;       // local t in [0,5)
            float v = fmaxf(rmax, __shfl_xor(rmax, 32));
            if (hi == 0)
                atomicMax(&part[(aw*32 + l31) * 5 + tl], fenc(v));
            rmax = NINF;
        }
        asm volatile("" ::: "memory");
        __builtin_amdgcn_s_barrier();    // buf[cur] reads done before restage
    }

    __syncthreads();

    float sum = 0.f;
    for (int i = tid; i < 320; i += 256) sum += fdec(part[i]);
    #pragma unroll
    for (int m = 1; m < 64; m <<= 1) {
        sum += __shfl_xor(sum, m);
        nn  += __shfl_xor(nn, m);
    }
    if (lane == 0) { red[wid] = sum; red[4 + wid] = nn; }
    __syncthreads();
    if (tid == 0) {
        float S = 0.f, N = 0.f;
        #pragma unroll
        for (int w = 0; w < 4; ++w) { S += red[w]; N += red[4 + w]; }
        float* cp = (float*)(ws + WS_CP_OFF);
        const int idx = (x2*16 + y)*2 + h;       // [0,1024)
        cp[idx]        = S;
        cp[1024 + idx] = N;
    }
}

// ---------------------------------------------------------------------------
// final: 16x16 InfoNCE + regularizers -> 3 scalars
__global__ void final_kernel(const char* __restrict__ ws,
                             const float* __restrict__ temp,
                             float* __restrict__ out)
{
    __shared__ float cs[16][17];
    __shared__ float nnred[256];
    __shared__ float lse_r[16], lse_c[16];
    const int tid = threadIdx.x;
    const float T = temp[0];
    const float* cp = (const float*)(ws + WS_CP_OFF);
    const int x = tid >> 4, yy = tid & 15;
    float sclip = 0.f;
    #pragma unroll
    for (int a = 0; a < 2; ++a)
        #pragma unroll
        for (int hh = 0; hh < 2; ++hh)
            sclip += cp[(((2*x + a)*16 + yy)*2) + hh];
    cs[x][yy] = sclip / (1280.0f * T);
    float n = 0.f;
    #pragma unroll
    for (int j = 0; j < 4; ++j) n += cp[1024 + tid + j*256];
    nnred[tid] = n;
    __syncthreads();
    for (int s = 128; s > 0; s >>= 1) {
        if (tid < s) nnred[tid] += nnred[tid + s];
        __syncthreads();
    }
    if (tid < 16) {
        float m = NINF;
        for (int j = 0; j < 16; ++j) m = fmaxf(m, cs[tid][j]);
        float s = 0.f;
        for (int j = 0; j < 16; ++j) s += expf(cs[tid][j] - m);
        lse_r[tid] = m + logf(s);
    } else if (tid < 32) {
        const int c = tid - 16;
        float m = NINF;
        for (int j = 0; j < 16; ++j) m = fmaxf(m, cs[j][c]);
        float s = 0.f;
        for (int j = 0; j < 16; ++j) s += expf(cs[j][c] - m);
        lse_c[c] = m + logf(s);
    }
    __syncthreads();
    if (tid == 0) {
        float acc = 0.f;
        for (int i = 0; i < 16; ++i)
            acc += (lse_r[i] - cs[i][i]) + (lse_c[i] - cs[i][i]);
        const float contrastive = 0.5f * acc * (1.0f / 16.0f);
        const float l_nonneg = nnred[0] / (64225280.0f * T * T);
        const float lt = logf(T);
        float tl = fmaxf(-lt, 0.f); tl = tl * tl; tl = tl * tl;
        float th = fmaxf(lt - 1.0986122886681098f, 0.f); th = th * th; th = th * th;
        const float reg = l_nonneg + tl + th;
        out[0] = contrastive + 0.3f * reg;
        out[1] = contrastive;
        out[2] = reg;
    }
}

// ---------------------------------------------------------------------------
extern "C" void kernel_launch(void* const* d_in, const int* in_sizes, int n_in,
                              void* d_out, int out_size, void* d_ws, size_t ws_size,
                              hipStream_t stream)
{
    const float* audio  = (const float*)d_in[0];
    const float* visual = (const float*)d_in[1];
    const float* temp   = (const float*)d_in[2];
    char* ws = (char*)d_ws;

    prep_kernel<<<5376, 256, 0, stream>>>(audio, visual, ws);   // 43008 rows / 2 per wave
    main_kernel<<<1024, 256, 0, stream>>>(ws);                  // (x2, y, t-half)
    final_kernel<<<1, 256, 0, stream>>>(ws, temp, (float*)d_out);
}